// Round 6
// baseline (200.404 us; speedup 1.0000x reference)
//
#include <hip/hip_runtime.h>
#include <stdint.h>

typedef __attribute__((ext_vector_type(4))) float float4v;

#define D 4096
#define R 16
#define NW 192     // adapters
#define LB 1280    // lora rows
#define NBL 256
#define MAXB 32    // max bucket size (actual max ~16)
#define TQ 8       // x-tile rows staged in LDS per iteration
#define DQ 1024    // d-quarter width

// ---------------- K1: hpart[b][q][r] = x[xid_b] . A[w]  (d-quarter q) ------
// Block (w,q), 256 threads. Thread t: quad g=t>>2 (d-groups), class c=t&3
// (r = 4c..4c+3). A-quarter lives in 16 float4 regs. x rows staged in LDS
// tiles of 8 so the row loop never touches global memory.
__global__ __launch_bounds__(256) void h_kernel(
    const float* __restrict__ x,
    const float* __restrict__ A,
    const int* __restrict__ xids,
    const int* __restrict__ wids,
    float* __restrict__ hpart)   // [LB][4][16]
{
    const int w = blockIdx.x >> 2;
    const int q = blockIdx.x & 3;
    const int t = threadIdx.x;
    const int lane = t & 63;
    const int wave = t >> 6;
    const int g = t >> 2;
    const int c = t & 3;

    __shared__ int list[MAXB], xidl[MAXB];
    __shared__ int cnt;
    __shared__ float xs[TQ][DQ];
    __shared__ float hws[TQ][4][R];

    if (t == 0) cnt = 0;
    __syncthreads();
    for (int i = t; i < LB; i += 256)
        if (wids[i] == w) { int p = atomicAdd(&cnt, 1); if (p < MAXB) list[p] = i; }
    __syncthreads();
    const int n = cnt > MAXB ? MAXB : cnt;
    if (n == 0) return;
    if (t < n) xidl[t] = xids[list[t]];

    // A-quarter into registers: a[k][j] = A[4g+256k+j][4c..4c+3]
    const float4v* af = (const float4v*)(A + ((size_t)w * D + q * DQ) * R);
    float4v a[4][4];
    #pragma unroll
    for (int k = 0; k < 4; ++k)
        #pragma unroll
        for (int j = 0; j < 4; ++j)
            a[k][j] = af[16 * g + 1024 * k + 4 * j + c];

    for (int tb = 0; tb < n; tb += TQ) {
        const int T = min(TQ, n - tb);
        __syncthreads();                      // xs/hws safe to overwrite, xidl ready
        for (int i = 0; i < T; ++i) {
            float4v v = *(const float4v*)(x + (size_t)xidl[tb + i] * D + q * DQ + 4 * t);
            *(float4v*)&xs[i][4 * t] = v;     // coalesced stage
        }
        __syncthreads();

        for (int i = 0; i < T; ++i) {
            float4v xv[4];
            #pragma unroll
            for (int k = 0; k < 4; ++k)
                xv[k] = *(const float4v*)&xs[i][4 * g + 256 * k];  // b128, 4-way bcast
            float h0 = 0.f, h1 = 0.f, h2 = 0.f, h3 = 0.f;
            #pragma unroll
            for (int k = 0; k < 4; ++k)
                #pragma unroll
                for (int j = 0; j < 4; ++j) {
                    const float xd = xv[k][j];
                    h0 += xd * a[k][j][0];
                    h1 += xd * a[k][j][1];
                    h2 += xd * a[k][j][2];
                    h3 += xd * a[k][j][3];
                }
            // reduce over the 16 in-wave d-groups (offsets preserve c = lane&3)
            #pragma unroll
            for (int off = 4; off <= 32; off <<= 1) {
                h0 += __shfl_xor(h0, off, 64);
                h1 += __shfl_xor(h1, off, 64);
                h2 += __shfl_xor(h2, off, 64);
                h3 += __shfl_xor(h3, off, 64);
            }
            if (lane < 4) {                   // lane == c here
                float4v hv = {h0, h1, h2, h3};
                *(float4v*)&hws[i][wave][4 * lane] = hv;
            }
        }
        __syncthreads();
        for (int idx = t; idx < T * R; idx += 256) {
            const int i = idx >> 4, r = idx & 15;
            const float s = hws[i][0][r] + hws[i][1][r] + hws[i][2][r] + hws[i][3][r];
            hpart[(size_t)list[tb + i] * 64 + q * 16 + r] = s;   // 64B-coalesced groups
        }
    }
}

// ---------------- K2: y = 2*h.B, scatter/accumulate into out ---------------
// Block (w,q): thread owns d-quad q*1024+4t. B-quarter in 16 float4 regs.
// Shared-segment rows accumulate via native f32 atomics (out pre-zeroed);
// pass-through rows plain-store.
__global__ __launch_bounds__(256) void y_kernel(
    const float* __restrict__ B,
    const int* __restrict__ wids,
    const float* __restrict__ hpart,
    float* __restrict__ out)
{
    const int w = blockIdx.x >> 2;
    const int q = blockIdx.x & 3;
    const int t = threadIdx.x;

    __shared__ int list[MAXB];
    __shared__ int cnt;
    __shared__ float hl[MAXB][R];

    if (t == 0) cnt = 0;
    __syncthreads();
    for (int i = t; i < LB; i += 256)
        if (wids[i] == w) { int p = atomicAdd(&cnt, 1); if (p < MAXB) list[p] = i; }
    __syncthreads();
    const int n = cnt > MAXB ? MAXB : cnt;
    if (n == 0) return;

    const float* Bw = B + (size_t)w * R * D + q * DQ + 4 * t;
    float4v breg[R];
    #pragma unroll
    for (int r = 0; r < R; ++r) breg[r] = *(const float4v*)(Bw + (size_t)r * D);

    for (int idx = t; idx < n * R; idx += 256) {
        const int i = idx >> 4, r = idx & 15;
        const float* hp = hpart + (size_t)list[i] * 64 + r;
        hl[i][r] = (hp[0] + hp[16]) + (hp[32] + hp[48]);
    }
    __syncthreads();

    for (int i = 0; i < n; ++i) {
        const int b = list[i];
        float4v acc = {0.f, 0.f, 0.f, 0.f};
        #pragma unroll
        for (int r = 0; r < R; ++r) {
            const float hr = hl[i][r];        // LDS broadcast (same addr all lanes)
            acc[0] += hr * breg[r][0];
            acc[1] += hr * breg[r][1];
            acc[2] += hr * breg[r][2];
            acc[3] += hr * breg[r][3];
        }
        #pragma unroll
        for (int k = 0; k < 4; ++k) acc[k] *= 2.0f;

        if (b < NBL * 4) {
            float* o = out + (size_t)(b >> 2) * D + q * DQ + 4 * t;
            unsafeAtomicAdd(o + 0, acc[0]);
            unsafeAtomicAdd(o + 1, acc[1]);
            unsafeAtomicAdd(o + 2, acc[2]);
            unsafeAtomicAdd(o + 3, acc[3]);
        } else {
            *(float4v*)(out + (size_t)(NBL + (b - NBL * 4)) * D + q * DQ + 4 * t) = acc;
        }
    }
}

extern "C" void kernel_launch(void* const* d_in, const int* in_sizes, int n_in,
                              void* d_out, int out_size, void* d_ws, size_t ws_size,
                              hipStream_t stream) {
    const float* x    = (const float*)d_in[0];
    const float* A    = (const float*)d_in[1];
    const float* B    = (const float*)d_in[2];
    const int*   xids = (const int*)d_in[3];
    const int*   wids = (const int*)d_in[4];
    float*       out  = (float*)d_out;

    float* hpart = (float*)d_ws;   // [LB][4][16] f32 = 327 KB

    // zero the shared-segment rows (atomic accumulation targets)
    hipMemsetAsync(out, 0, (size_t)NBL * D * sizeof(float), stream);

    hipLaunchKernelGGL(h_kernel, dim3(NW * 4), dim3(256), 0, stream,
                       x, A, xids, wids, hpart);
    hipLaunchKernelGGL(y_kernel, dim3(NW * 4), dim3(256), 0, stream,
                       B, wids, hpart, out);
}

// Round 7
// 158.184 us; speedup vs baseline: 1.2669x; 1.2669x over previous
//
#include <hip/hip_runtime.h>
#include <stdint.h>

typedef __attribute__((ext_vector_type(4))) float float4v;

#define D 4096
#define R 16
#define NW 192     // adapters
#define LB 1280    // lora rows
#define NBL 256
#define MAXB 32    // max bucket size (actual max ~16)
#define TQ 8       // x-tile rows staged in LDS per iteration
#define DQ 1024    // d-quarter width

// ---------------- K1: hpart[b][q][r] = x[xid_b] . A[w]  (d-quarter q) ------
// Block (w,q), 256 threads. Thread t: quad g=t>>2 (d-groups), class c=t&3
// (r = 4c..4c+3). A-quarter lives in 16 float4 regs. x rows staged in LDS
// tiles of 8 so the row loop never touches global memory.
__global__ __launch_bounds__(256) void h_kernel(
    const float* __restrict__ x,
    const float* __restrict__ A,
    const int* __restrict__ xids,
    const int* __restrict__ wids,
    float* __restrict__ hpart)   // [LB][4][16]
{
    const int w = blockIdx.x >> 2;
    const int q = blockIdx.x & 3;
    const int t = threadIdx.x;
    const int lane = t & 63;
    const int wave = t >> 6;
    const int g = t >> 2;
    const int c = t & 3;

    __shared__ int list[MAXB], xidl[MAXB];
    __shared__ int cnt;
    __shared__ float xs[TQ][DQ];
    __shared__ float hws[TQ][4][R];

    if (t == 0) cnt = 0;
    __syncthreads();
    for (int i = t; i < LB; i += 256)
        if (wids[i] == w) { int p = atomicAdd(&cnt, 1); if (p < MAXB) list[p] = i; }
    __syncthreads();
    const int n = cnt > MAXB ? MAXB : cnt;
    if (n == 0) return;
    if (t < n) xidl[t] = xids[list[t]];

    // A-quarter into registers: a[k][j] = A[4g+256k+j][4c..4c+3]
    const float4v* af = (const float4v*)(A + ((size_t)w * D + q * DQ) * R);
    float4v a[4][4];
    #pragma unroll
    for (int k = 0; k < 4; ++k)
        #pragma unroll
        for (int j = 0; j < 4; ++j)
            a[k][j] = af[16 * g + 1024 * k + 4 * j + c];

    for (int tb = 0; tb < n; tb += TQ) {
        const int T = min(TQ, n - tb);
        __syncthreads();                      // xs/hws safe to overwrite, xidl ready
        for (int i = 0; i < T; ++i) {
            float4v v = *(const float4v*)(x + (size_t)xidl[tb + i] * D + q * DQ + 4 * t);
            *(float4v*)&xs[i][4 * t] = v;     // coalesced stage
        }
        __syncthreads();

        for (int i = 0; i < T; ++i) {
            float4v xv[4];
            #pragma unroll
            for (int k = 0; k < 4; ++k)
                xv[k] = *(const float4v*)&xs[i][4 * g + 256 * k];  // b128, 4-way bcast
            float h0 = 0.f, h1 = 0.f, h2 = 0.f, h3 = 0.f;
            #pragma unroll
            for (int k = 0; k < 4; ++k)
                #pragma unroll
                for (int j = 0; j < 4; ++j) {
                    const float xd = xv[k][j];
                    h0 += xd * a[k][j][0];
                    h1 += xd * a[k][j][1];
                    h2 += xd * a[k][j][2];
                    h3 += xd * a[k][j][3];
                }
            // reduce over the 16 in-wave d-groups (offsets preserve c = lane&3)
            #pragma unroll
            for (int off = 4; off <= 32; off <<= 1) {
                h0 += __shfl_xor(h0, off, 64);
                h1 += __shfl_xor(h1, off, 64);
                h2 += __shfl_xor(h2, off, 64);
                h3 += __shfl_xor(h3, off, 64);
            }
            if (lane < 4) {                   // lane == c here
                float4v hv = {h0, h1, h2, h3};
                *(float4v*)&hws[i][wave][4 * lane] = hv;
            }
        }
        __syncthreads();
        for (int idx = t; idx < T * R; idx += 256) {
            const int i = idx >> 4, r = idx & 15;
            const float s = hws[i][0][r] + hws[i][1][r] + hws[i][2][r] + hws[i][3][r];
            hpart[(size_t)list[tb + i] * 64 + q * 16 + r] = s;   // 64B-coalesced groups
        }
    }
}

// ---------------- K2: y = 2*h.B; unique-writer stores (NO atomics) ---------
// Block (w,q): thread owns d-quad q*1024+4t. B-quarter in 16 float4 regs.
// Shared-segment rows (b < 1024) plain-store their full y into ybuf[b];
// pass-through rows store directly to out rows 256..511.
__global__ __launch_bounds__(256) void y_kernel(
    const float* __restrict__ B,
    const int* __restrict__ wids,
    const float* __restrict__ hpart,
    float* __restrict__ ybuf,    // [1024][D]
    float* __restrict__ out)     // [512][D]
{
    const int w = blockIdx.x >> 2;
    const int q = blockIdx.x & 3;
    const int t = threadIdx.x;

    __shared__ int list[MAXB];
    __shared__ int cnt;
    __shared__ float hl[MAXB][R];

    if (t == 0) cnt = 0;
    __syncthreads();
    for (int i = t; i < LB; i += 256)
        if (wids[i] == w) { int p = atomicAdd(&cnt, 1); if (p < MAXB) list[p] = i; }
    __syncthreads();
    const int n = cnt > MAXB ? MAXB : cnt;
    if (n == 0) return;

    const float* Bw = B + (size_t)w * R * D + q * DQ + 4 * t;
    float4v breg[R];
    #pragma unroll
    for (int r = 0; r < R; ++r) breg[r] = *(const float4v*)(Bw + (size_t)r * D);

    for (int idx = t; idx < n * R; idx += 256) {
        const int i = idx >> 4, r = idx & 15;
        const float* hp = hpart + (size_t)list[i] * 64 + r;
        hl[i][r] = (hp[0] + hp[16]) + (hp[32] + hp[48]);
    }
    __syncthreads();

    for (int i = 0; i < n; ++i) {
        const int b = list[i];
        float4v acc = {0.f, 0.f, 0.f, 0.f};
        #pragma unroll
        for (int r = 0; r < R; ++r) {
            const float hr = hl[i][r];        // LDS broadcast (same addr all lanes)
            acc[0] += hr * breg[r][0];
            acc[1] += hr * breg[r][1];
            acc[2] += hr * breg[r][2];
            acc[3] += hr * breg[r][3];
        }
        #pragma unroll
        for (int k = 0; k < 4; ++k) acc[k] *= 2.0f;

        if (b < NBL * 4) {
            *(float4v*)(ybuf + (size_t)b * D + q * DQ + 4 * t) = acc;   // unique writer
        } else {
            *(float4v*)(out + (size_t)(NBL + (b - NBL * 4)) * D + q * DQ + 4 * t) = acc;
        }
    }
}

// ---------------- K3: out[o] = sum of ybuf[4o..4o+3] (rows 0..255) ---------
__global__ __launch_bounds__(256) void sum4_kernel(
    const float* __restrict__ ybuf,
    float* __restrict__ out)
{
    const int o = blockIdx.x >> 2;            // 0..255
    const int q = blockIdx.x & 3;             // d-quarter
    const int col = q * DQ + 4 * threadIdx.x;
    const float* y0 = ybuf + (size_t)(4 * o) * D + col;
    float4v v0 = *(const float4v*)(y0);
    float4v v1 = *(const float4v*)(y0 + D);
    float4v v2 = *(const float4v*)(y0 + 2 * D);
    float4v v3 = *(const float4v*)(y0 + 3 * D);
    float4v s;
    #pragma unroll
    for (int k = 0; k < 4; ++k) s[k] = (v0[k] + v1[k]) + (v2[k] + v3[k]);
    *(float4v*)(out + (size_t)o * D + col) = s;
}

extern "C" void kernel_launch(void* const* d_in, const int* in_sizes, int n_in,
                              void* d_out, int out_size, void* d_ws, size_t ws_size,
                              hipStream_t stream) {
    const float* x    = (const float*)d_in[0];
    const float* A    = (const float*)d_in[1];
    const float* B    = (const float*)d_in[2];
    const int*   xids = (const int*)d_in[3];
    const int*   wids = (const int*)d_in[4];
    float*       out  = (float*)d_out;

    // ws layout: hpart [LB][64] f32 (327 KB) | ybuf [1024][4096] f32 (16.8 MB)
    float* hpart = (float*)d_ws;
    float* ybuf  = hpart + (size_t)LB * 64;

    hipLaunchKernelGGL(h_kernel, dim3(NW * 4), dim3(256), 0, stream,
                       x, A, xids, wids, hpart);
    hipLaunchKernelGGL(y_kernel, dim3(NW * 4), dim3(256), 0, stream,
                       B, wids, hpart, ybuf, out);
    hipLaunchKernelGGL(sum4_kernel, dim3(NBL * 4), dim3(256), 0, stream,
                       ybuf, out);
}